// Round 6
// baseline (395.050 us; speedup 1.0000x reference)
//
#include <hip/hip_runtime.h>
#include <hip/hip_bf16.h>
#include <math.h>
#include <stdint.h>

// Disable FP contraction: tie-breaking (quality = 1e8 - area, ulp=8 at 1e8)
// and decode must bit-match the mul-then-round numpy reference.
#pragma clang fp contract(off)

#define NB   16
#define NC   20
#define NM   64
#define NT   21504
#define OFF1 16384
#define OFF2 20480
#define TOPK 1000
#define DELTA_OFF 80000L
#define CTR_OFF   1456256L

// workspace layout (float units)
#define WS_SCORES   0L
#define WS_BOXESW   344064L
#define WS_CIDW     1720320L
#define WS_TOPSC    2064384L
#define WS_TOPBOX   2080768L
#define WS_TOPSHIFT 2146304L
#define WS_TOPAREA  2211840L
#define WS_ACT      2228224L   // 256 x u64
#define WS_CNT      2228736L   // 16 x u32 arrival counters
#define WS_MATRIX   2229248L   // 16*1024*16 u64 = 2 MB (own region: no aliasing races)

// ---------- dtype helpers (bf: 0 = float32, 1 = bf16) ----------
__device__ __forceinline__ int detect_bf(const void* locs0) {
  unsigned w = *(const unsigned*)locs0;      // f32 4.0 = 0x40800000 (low16==0)
  return ((w & 0xFFFFu) == 0u) ? 0 : 1;
}
__device__ __forceinline__ float ldin(const void* p, long i, int bf) {
  if (bf) return __uint_as_float(((unsigned)((const unsigned short*)p)[i]) << 16);
  return ((const float*)p)[i];
}
__device__ __forceinline__ unsigned short f2bf(float v) {
  unsigned w = __float_as_uint(v);
  return (unsigned short)((w + 0x7FFFu + ((w >> 16) & 1u)) >> 16);  // RNE
}
__device__ __forceinline__ void stout(void* p, long i, float v, int bf) {
  if (bf) ((unsigned short*)p)[i] = f2bf(v);
  else    ((float*)p)[i] = v;
}

// ---------- K1: fused targets + scores/decode ----------
__global__ __launch_bounds__(256)
void k_main(const void* locs0, const void* locs1, const void* locs2,
            const void* gt,
            const void* cls0, const void* cls1, const void* cls2,
            const void* reg0, const void* reg1, const void* reg2,
            const void* ctr0, const void* ctr1, const void* ctr2,
            void* out, float* scores, float* boxesw, float* cidw) {
  __shared__ float sgt[NM * 5];
  const int bf  = detect_bf(locs0);
  const int b   = blockIdx.y;
  const int blk = blockIdx.x;
  const int tid = threadIdx.x;
  const int n   = blk * 256 + tid;

  const void *L, *CL, *RG, *CT; int NL, base; float stride, lower, upper;
  if (blk < 64)      { L=locs0; CL=cls0; RG=reg0; CT=ctr0; NL=16384; base=0;    stride=8.f;  lower=0.f;   upper=64.f; }
  else if (blk < 80) { L=locs1; CL=cls1; RG=reg1; CT=ctr1; NL=4096;  base=OFF1; stride=16.f; lower=64.f;  upper=128.f; }
  else               { L=locs2; CL=cls2; RG=reg2; CT=ctr2; NL=1024;  base=OFF2; stride=32.f; lower=128.f; upper=INFINITY; }
  const int nl = n - base;

  for (int i = tid; i < NM * 5; i += 256) sgt[i] = ldin(gt, (long)b * NM * 5 + i, bf);
  __syncthreads();

  float cx = ldin(L, (long)nl * 2 + 0, bf);
  float cy = ldin(L, (long)nl * 2 + 1, bf);

  // ---- GT matching / targets ----
  float best = -1.0f; int bi = 0;              // argmax-first (strict >)
  for (int m = 0; m < NM; ++m) {
    float g0 = sgt[m*5+0], g1 = sgt[m*5+1], g2 = sgt[m*5+2], g3 = sgt[m*5+3];
    float l = cx - g0, t = cy - g1, r = g2 - cx, d = g3 - cy;
    float mn = fminf(fminf(l, t), fminf(r, d));
    float mx = fmaxf(fmaxf(l, t), fmaxf(r, d));
    bool  ok = (mn > 0.f) && (mx > lower) && (mx < upper);
    float area = (g2 - g0) * (g3 - g1);
    float q = ok ? (100000000.0f - area) : 0.f;
    if (q > best) { best = q; bi = m; }
  }
  float d0, d1, d2, d3, ctrv;
  if (best < 1e-5f) {
    d0 = d1 = d2 = d3 = -1.f; ctrv = -1.f;
  } else {
    float m0 = sgt[bi*5+0], m1 = sgt[bi*5+1], m2 = sgt[bi*5+2], m3 = sgt[bi*5+3];
    d0 = (cx - m0) / stride; d1 = (cy - m1) / stride;
    d2 = (m2 - cx) / stride; d3 = (m3 - cy) / stride;
    float mnlr = fminf(d0, d2), mntb = fminf(d1, d3);
    float mxlr = fmaxf(d0, d2), mxtb = fmaxf(d1, d3);
    ctrv = sqrtf((mnlr * mntb) / (mxlr * mxtb));
  }
  long dbase = DELTA_OFF + ((long)b * NT + n) * 4;
  if (!bf) {
    *(float4*)((float*)out + dbase) = make_float4(d0, d1, d2, d3);
  } else {
    ushort4 v; v.x = f2bf(d0); v.y = f2bf(d1); v.z = f2bf(d2); v.w = f2bf(d3);
    *(ushort4*)((unsigned short*)out + dbase) = v;
  }
  stout(out, CTR_OFF + (long)b * NT + n, ctrv, bf);

  // ---- scores: argmax over sigmoid == argmax over logits (monotone) ----
  float ct  = ldin(CT, (long)b * NL + nl, bf);
  float sct = 1.0f / (1.0f + expf(-ct));

  float cl[NC];
  long cb = ((long)b * NL + nl) * NC;
  if (!bf) {
    const float4* p = (const float4*)((const float*)CL + cb);   // cb*4 % 16 == 0
#pragma unroll
    for (int i = 0; i < 5; ++i) {
      float4 q = p[i];
      cl[4*i+0] = q.x; cl[4*i+1] = q.y; cl[4*i+2] = q.z; cl[4*i+3] = q.w;
    }
  } else {
    const uint2* p = (const uint2*)((const unsigned short*)CL + cb);  // cb*2 % 8 == 0
#pragma unroll
    for (int i = 0; i < 5; ++i) {
      uint2 q = p[i];
      cl[4*i+0] = __uint_as_float((q.x & 0xFFFFu) << 16);
      cl[4*i+1] = __uint_as_float(q.x & 0xFFFF0000u);
      cl[4*i+2] = __uint_as_float((q.y & 0xFFFFu) << 16);
      cl[4*i+3] = __uint_as_float(q.y & 0xFFFF0000u);
    }
  }
  float vmax = cl[0], v2 = -INFINITY; int ci = 0;
#pragma unroll
  for (int c = 1; c < NC; ++c) {
    if (cl[c] > vmax) { v2 = vmax; vmax = cl[c]; ci = c; }
    else if (cl[c] > v2) v2 = cl[c];
  }
  float smax;
  if (vmax - v2 < 1e-3f) {
    // sigmoid-plateau risk: replicate the reference loop exactly (strict >, first idx)
    smax = -1.0f; ci = 0;
    for (int c = 0; c < NC; ++c) {
      float sv = 1.0f / (1.0f + expf(-cl[c]));
      float s  = sqrtf(sv * sct);
      if (s > smax) { smax = s; ci = c; }
    }
  } else {
    float sv = 1.0f / (1.0f + expf(-vmax));
    smax = sqrtf(sv * sct);      // == ref's max: RN is monotone under *sct and sqrt
  }

  // ---- decode ----
  float r0, r1, r2, r3;
  long rbase = ((long)b * NL + nl) * 4;
  if (!bf) {
    float4 rv = *(const float4*)((const float*)RG + rbase);
    r0 = rv.x; r1 = rv.y; r2 = rv.z; r3 = rv.w;
  } else {
    uint2 rw = *(const uint2*)((const unsigned short*)RG + rbase);
    r0 = __uint_as_float((rw.x & 0xFFFFu) << 16); r1 = __uint_as_float(rw.x & 0xFFFF0000u);
    r2 = __uint_as_float((rw.y & 0xFFFFu) << 16); r3 = __uint_as_float(rw.y & 0xFFFF0000u);
  }
  r0 = fmaxf(r0, 0.f); r1 = fmaxf(r1, 0.f); r2 = fmaxf(r2, 0.f); r3 = fmaxf(r3, 0.f);
  long o = (long)b * NT + n;
  scores[o] = smax;
  *(float4*)(boxesw + o * 4) =
      make_float4(cx - r0 * stride, cy - r1 * stride, cx + r2 * stride, cy + r3 * stride);
  cidw[o] = (float)ci;
}

// ---------- wave64 inclusive scan ----------
__device__ __forceinline__ unsigned wscan(unsigned v, int lane) {
  for (int off = 1; off < 64; off <<= 1) {
    unsigned u = __shfl_up(v, off);
    if (lane >= off) v += u;
  }
  return v;
}

// ---------- K2: exact top-1000 (2-level histogram + hybrid bitonic) ----------
__global__ __launch_bounds__(1024)
void k_select(const float* scores, const float* boxesw, const float* cidw,
              float* topScore, float* topBox, float* topShift, float* topArea,
              unsigned long long* actInit, unsigned* counters) {
  const int b    = blockIdx.x;
  const int tid  = threadIdx.x;
  const int wid  = tid >> 6;
  const int lane = tid & 63;
  const float* sb = scores + (long)b * NT;

  __shared__ unsigned hist[8192];                       // 32 KB; aliased below
  unsigned long long* selKeys = (unsigned long long*)hist;  // [1024], alias (phase 2)
  __shared__ unsigned wsum[16];
  __shared__ unsigned sTop, sBefore, sSub, selCnt;
  __shared__ float redf[16];
  __shared__ float sMaxC;

  if (tid == 0) counters[b] = 0u;   // arrival counter for k_iou_scan (ws is poisoned)

  unsigned inv[21];
#pragma unroll
  for (int k = 0; k < 21; ++k)
    inv[k] = ~__float_as_uint(sb[tid + k * 1024]);

  // --- level 1: histogram of inv>>17 (top 2 bits always 11 -> 8192 bins) ---
  for (int i = tid; i < 8192; i += 1024) hist[i] = 0u;
  __syncthreads();
#pragma unroll
  for (int k = 0; k < 21; ++k)
    atomicAdd(&hist[(inv[k] >> 17) - 0x6000u], 1u);
  __syncthreads();
  {
    unsigned hloc[8], s0 = 0;
#pragma unroll
    for (int j = 0; j < 8; ++j) { hloc[j] = hist[8 * tid + j]; s0 += hloc[j]; }
    unsigned sc = wscan(s0, lane);
    if (lane == 63) wsum[wid] = sc;
    __syncthreads();
    unsigned basev = 0;
    for (int w = 0; w < wid; ++w) basev += wsum[w];
    unsigned cumBefore = basev + sc - s0;
    if (cumBefore < TOPK && cumBefore + s0 >= TOPK) {
      unsigned c = cumBefore;
#pragma unroll
      for (int j = 0; j < 8; ++j) {
        if (c + hloc[j] >= TOPK) { sTop = (8 * tid + j) + 0x6000u; sBefore = c; break; }
        c += hloc[j];
      }
    }
  }
  __syncthreads();
  const unsigned topBits = sTop;
  const unsigned r = TOPK - sBefore;

  // --- level 2: histogram of bits 16..4 within boundary bin ---
  for (int i = tid; i < 8192; i += 1024) hist[i] = 0u;
  __syncthreads();
#pragma unroll
  for (int k = 0; k < 21; ++k)
    if ((inv[k] >> 17) == topBits) atomicAdd(&hist[(inv[k] >> 4) & 0x1FFFu], 1u);
  __syncthreads();
  {
    unsigned hloc[8], s0 = 0;
#pragma unroll
    for (int j = 0; j < 8; ++j) { hloc[j] = hist[8 * tid + j]; s0 += hloc[j]; }
    unsigned sc = wscan(s0, lane);
    if (lane == 63) wsum[wid] = sc;
    __syncthreads();
    unsigned basev = 0;
    for (int w = 0; w < wid; ++w) basev += wsum[w];
    unsigned cumBefore = basev + sc - s0;
    if (cumBefore < r && cumBefore + s0 >= r) {
      unsigned c = cumBefore;
#pragma unroll
      for (int j = 0; j < 8; ++j) {
        if (c + hloc[j] >= r) { sSub = 8 * tid + j; break; }
        c += hloc[j];
      }
    }
  }
  __syncthreads();
  const unsigned long long cutEnd =
      ((unsigned long long)topBits << 17) | ((unsigned long long)(sSub + 1u) << 4);
  if (tid == 0) selCnt = 0u;
  __syncthreads();   // hist reads done; selKeys alias safe

#pragma unroll
  for (int k = 0; k < 21; ++k)
    if ((unsigned long long)inv[k] < cutEnd) {
      unsigned p = atomicAdd(&selCnt, 1u);
      if (p < 1024u) selKeys[p] = ((unsigned long long)inv[k] << 32) | (unsigned)(tid + k * 1024);
    }
  __syncthreads();
  unsigned total = selCnt < 1024u ? selCnt : 1024u;
  unsigned long long key =
      ((unsigned)tid < total) ? selKeys[tid] : 0xFFFFFFFFFFFFFFFFull;
  __syncthreads();

  // --- hybrid bitonic sort ascending: (inv asc, idx asc) == (score desc, idx asc) ---
  for (unsigned k = 2; k <= 1024; k <<= 1) {
    for (unsigned j = k >> 1; j > 0; j >>= 1) {
      unsigned long long other;
      if (j >= 64) {
        selKeys[tid] = key; __syncthreads();
        other = selKeys[tid ^ j]; __syncthreads();
      } else {
        other = __shfl(key, (int)(lane ^ j));
      }
      bool up = ((tid & k) == 0);
      bool takeMin = (((tid & j) == 0) == up);
      key = takeMin ? (key < other ? key : other) : (key > other ? key : other);
    }
  }

  // --- epilogue: gather boxes, max_coord, shift, write top arrays ---
  float sc = __uint_as_float(~(unsigned)(key >> 32));
  float4 bv = make_float4(0.f, 0.f, 0.f, 0.f);
  float cid = 0.f;
  if (tid < TOPK) {
    long o = (long)b * NT + (unsigned)key;
    bv = *(const float4*)(boxesw + o * 4);
    cid = cidw[o];
  } else sc = 0.f;

  float loc = (tid < TOPK)
      ? ((sc > 0.3f) ? fmaxf(fmaxf(bv.x, bv.y), fmaxf(bv.z, bv.w)) : 0.0f)
      : -INFINITY;
  for (int o = 32; o > 0; o >>= 1) loc = fmaxf(loc, __shfl_down(loc, o));
  if (lane == 0) redf[wid] = loc;
  __syncthreads();
  if (tid == 0) {
    float m = redf[0];
    for (int w = 1; w < 16; ++w) m = fmaxf(m, redf[w]);
    sMaxC = m;
  }
  __syncthreads();

  float offm = sMaxC + 1.0f;
  long tb = (long)b * 1024 + tid;
  if (tid < TOPK) {
    float o4 = cid * offm;
    float s0 = bv.x + o4, s1 = bv.y + o4, s2 = bv.z + o4, s3 = bv.w + o4;
    *(float4*)(topShift + tb * 4) = make_float4(s0, s1, s2, s3);
    topArea[tb]  = (s2 - s0) * (s3 - s1);
    *(float4*)(topBox + tb * 4) = bv;
    topScore[tb] = sc;
  } else {
    *(float4*)(topShift + tb * 4) = make_float4(0.f, 0.f, 0.f, 0.f);
    topArea[tb]  = 0.f;
    *(float4*)(topBox + tb * 4) = make_float4(0.f, 0.f, 0.f, 0.f);
    topScore[tb] = 0.f;
  }
  unsigned long long vb = __ballot((tid < TOPK) && (sc > 0.3f));
  if (lane == 0) actInit[b * 16 + wid] = vb;
}

// ---------- K3: parallel IoU bit-matrix + last-arriving block runs greedy scan ----------
// grid (32, NB). Block (wh,b) computes u32 word wh (cols wh*32..wh*32+31) for all
// upper-triangle rows. Arrival counter: 32nd block of batch b performs the scan.
// Cross-XCD visibility: writers __threadfence() (device-scope release) before the
// atomic; the scanning block uses volatile loads (bypass L1) after an acquire fence.
__global__ __launch_bounds__(1024)
void k_iou_scan(const float* topShift, const float* topArea,
                const float* topBox, const float* topScore,
                unsigned* matrix32, unsigned* counters,
                const unsigned long long* actInit,
                void* out, const void* locs0) {
  const int wh   = blockIdx.x;
  const int b    = blockIdx.y;
  const int tid  = threadIdx.x;
  const int wid  = tid >> 6;
  const int lane = tid & 63;
  const int jbase = wh * 32;

  __shared__ float jx0[32], jy0[32], jx1[32], jy1[32], ja[32];
  __shared__ unsigned long long rows[2][64][16];   // scan double-buffer (16 KB)
  __shared__ unsigned long long keepSh[16];
  __shared__ int sLast;

  // ---- Phase 1: IoU word compute (upper triangle only) ----
  if (tid < 32) {
    long tj = (long)b * 1024 + jbase + tid;
    float4 s = *(const float4*)(topShift + tj * 4);
    jx0[tid] = s.x; jy0[tid] = s.y; jx1[tid] = s.z; jy1[tid] = s.w;
    ja[tid] = topArea[tj];
  }
  __syncthreads();
  if (tid <= jbase + 31) {          // rows whose word touches the diagonal/upper
    long ti = (long)b * 1024 + tid;
    float4 si = *(const float4*)(topShift + ti * 4);
    float ai  = topArea[ti];
    unsigned word = 0u;
    for (int k = 0; k < 32; ++k) {
      float xx1 = fmaxf(si.x, jx0[k]);
      float yy1 = fmaxf(si.y, jy0[k]);
      float xx2 = fminf(si.z, jx1[k]);
      float yy2 = fminf(si.w, jy1[k]);
      float inter = fmaxf(xx2 - xx1, 0.f) * fmaxf(yy2 - yy1, 0.f);
      float iou = inter / (ai + ja[k] - inter);   // exact div: matches ref rounding
      if (!(iou <= 0.5f)) word |= (1u << k);      // NaN suppresses, like the ref
    }
    matrix32[((long)b * 1024 + tid) * 32 + wh] = word;
  }

  // ---- arrival: last block of this batch scans ----
  __syncthreads();
  __threadfence();                                 // release matrix words
  if (tid == 0) sLast = (atomicAdd(&counters[b], 1u) == 31u);
  __syncthreads();
  if (!sLast) return;
  __threadfence();                                 // acquire

  // ---- Phase 2: greedy scan (R4 k_scan logic; volatile = L1-bypass reads) ----
  const volatile unsigned long long* M =
      (const volatile unsigned long long*)matrix32 + (long)b * 1024 * 16;

  unsigned long long act = 0ull, keep = 0ull;
  if (wid == 0 && lane < 16) act = actInit[b * 16 + lane];

  for (int t = tid; t < 1024; t += 1024)
    rows[0][t >> 4][t & 15] = M[t];
  // (1024 threads, 1024 words: each thread loads exactly one)
  __syncthreads();

  int kept = 0;
  for (int c = 0; c < 16; ++c) {
    if (wid > 0) {
      if (c < 15) {
        for (int t = tid - 64; t < 1024; t += 960)
          rows[(c + 1) & 1][t >> 4][t & 15] = M[(long)(c + 1) * 1024 + t];
      }
    } else {
      unsigned long long cur = __shfl(act, c);
      while (cur && kept < 100) {
        int k = __ffsll(cur) - 1;
        ++kept;
        if (lane == c) keep |= (1ull << k);
        // garbage lower-tri words only clear bits j < picked idx, which are
        // already inactive (first-active order) — harmless.
        unsigned long long rrow = (lane < 16) ? rows[c & 1][k][lane] : 0ull;
        act &= ~rrow;                            // self-bit clears the picked box
        cur = __shfl(act, c);
      }
    }
    __syncthreads();
  }
  if (wid == 0 && lane < 16) keepSh[lane] = keep;
  __syncthreads();

  // ---- det write ----
  const int bf = detect_bf(locs0);
  if (tid < TOPK) {
    bool kp = (keepSh[tid >> 6] >> (tid & 63)) & 1ull;
    long tb = (long)b * 1024 + tid;
    float4 bx = *(const float4*)(topBox + tb * 4);
    float sc  = topScore[tb];
    long o = ((long)b * TOPK + tid) * 5;
    stout(out, o + 0, kp ? bx.x : 0.f, bf);
    stout(out, o + 1, kp ? bx.y : 0.f, bf);
    stout(out, o + 2, kp ? bx.z : 0.f, bf);
    stout(out, o + 3, kp ? bx.w : 0.f, bf);
    stout(out, o + 4, kp ? sc   : 0.f, bf);
  }
}

extern "C" void kernel_launch(void* const* d_in, const int* in_sizes, int n_in,
                              void* d_out, int out_size, void* d_ws, size_t ws_size,
                              hipStream_t stream) {
  const void* locs0 = d_in[0];
  const void* locs1 = d_in[1];
  const void* locs2 = d_in[2];
  const void* gt    = d_in[3];

  int ic[3], ir[3], it[3];
  if (n_in >= 13 && in_sizes[5] == 16 * 4096 * 20) {
    ic[0]=4; ic[1]=5; ic[2]=6;  ir[0]=7; ir[1]=8; ir[2]=9;  it[0]=10; it[1]=11; it[2]=12;
  } else {
    ic[0]=4; ic[1]=7; ic[2]=10; ir[0]=5; ir[1]=8; ir[2]=11; it[0]=6;  it[1]=9;  it[2]=12;
  }
  const void* cls0 = d_in[ic[0]]; const void* cls1 = d_in[ic[1]]; const void* cls2 = d_in[ic[2]];
  const void* reg0 = d_in[ir[0]]; const void* reg1 = d_in[ir[1]]; const void* reg2 = d_in[ir[2]];
  const void* ctr0 = d_in[it[0]]; const void* ctr1 = d_in[it[1]]; const void* ctr2 = d_in[it[2]];

  float* ws       = (float*)d_ws;
  float* scores   = ws + WS_SCORES;
  float* boxesw   = ws + WS_BOXESW;
  float* cidw     = ws + WS_CIDW;
  float* topScore = ws + WS_TOPSC;
  float* topBox   = ws + WS_TOPBOX;
  float* topShift = ws + WS_TOPSHIFT;
  float* topArea  = ws + WS_TOPAREA;
  unsigned long long* actInit  = (unsigned long long*)(ws + WS_ACT);
  unsigned*           counters = (unsigned*)(ws + WS_CNT);
  unsigned*           matrix32 = (unsigned*)(ws + WS_MATRIX);

  k_main<<<dim3(NT / 256, NB), 256, 0, stream>>>(locs0, locs1, locs2, gt,
                                                 cls0, cls1, cls2,
                                                 reg0, reg1, reg2,
                                                 ctr0, ctr1, ctr2,
                                                 d_out, scores, boxesw, cidw);
  k_select<<<NB, 1024, 0, stream>>>(scores, boxesw, cidw,
                                    topScore, topBox, topShift, topArea,
                                    actInit, counters);
  k_iou_scan<<<dim3(32, NB), 1024, 0, stream>>>(topShift, topArea,
                                                topBox, topScore,
                                                matrix32, counters, actInit,
                                                d_out, locs0);
}

// Round 7
// 204.284 us; speedup vs baseline: 1.9338x; 1.9338x over previous
//
#include <hip/hip_runtime.h>
#include <hip/hip_bf16.h>
#include <math.h>
#include <stdint.h>

// Disable FP contraction: tie-breaking (quality = 1e8 - area, ulp=8 at 1e8)
// and decode must bit-match the mul-then-round numpy reference.
#pragma clang fp contract(off)

#define NB   16
#define NC   20
#define NM   64
#define NT   21504
#define OFF1 16384
#define OFF2 20480
#define TOPK 1000
#define DELTA_OFF 80000L
#define CTR_OFF   1456256L

// workspace layout (float units)
#define WS_SCORES   0L
#define WS_BOXESW   344064L
#define WS_CIDW     1720320L

// ---------- dtype helpers (bf: 0 = float32, 1 = bf16) ----------
__device__ __forceinline__ int detect_bf(const void* locs0) {
  unsigned w = *(const unsigned*)locs0;      // f32 4.0 = 0x40800000 (low16==0)
  return ((w & 0xFFFFu) == 0u) ? 0 : 1;
}
__device__ __forceinline__ float ldin(const void* p, long i, int bf) {
  if (bf) return __uint_as_float(((unsigned)((const unsigned short*)p)[i]) << 16);
  return ((const float*)p)[i];
}
__device__ __forceinline__ unsigned short f2bf(float v) {
  unsigned w = __float_as_uint(v);
  return (unsigned short)((w + 0x7FFFu + ((w >> 16) & 1u)) >> 16);  // RNE
}
__device__ __forceinline__ void stout(void* p, long i, float v, int bf) {
  if (bf) ((unsigned short*)p)[i] = f2bf(v);
  else    ((float*)p)[i] = v;
}

// ---------- K1: fused targets + scores/decode (R4 version, proven) ----------
__global__ __launch_bounds__(256)
void k_main(const void* locs0, const void* locs1, const void* locs2,
            const void* gt,
            const void* cls0, const void* cls1, const void* cls2,
            const void* reg0, const void* reg1, const void* reg2,
            const void* ctr0, const void* ctr1, const void* ctr2,
            void* out, float* scores, float* boxesw, float* cidw) {
  __shared__ float sgt[NM * 5];
  const int bf  = detect_bf(locs0);
  const int b   = blockIdx.y;
  const int blk = blockIdx.x;
  const int tid = threadIdx.x;
  const int n   = blk * 256 + tid;

  const void *L, *CL, *RG, *CT; int NL, base; float stride, lower, upper;
  if (blk < 64)      { L=locs0; CL=cls0; RG=reg0; CT=ctr0; NL=16384; base=0;    stride=8.f;  lower=0.f;   upper=64.f; }
  else if (blk < 80) { L=locs1; CL=cls1; RG=reg1; CT=ctr1; NL=4096;  base=OFF1; stride=16.f; lower=64.f;  upper=128.f; }
  else               { L=locs2; CL=cls2; RG=reg2; CT=ctr2; NL=1024;  base=OFF2; stride=32.f; lower=128.f; upper=INFINITY; }
  const int nl = n - base;

  for (int i = tid; i < NM * 5; i += 256) sgt[i] = ldin(gt, (long)b * NM * 5 + i, bf);
  __syncthreads();

  float cx = ldin(L, (long)nl * 2 + 0, bf);
  float cy = ldin(L, (long)nl * 2 + 1, bf);

  // ---- GT matching / targets ----
  float best = -1.0f; int bi = 0;              // argmax-first (strict >)
  for (int m = 0; m < NM; ++m) {
    float g0 = sgt[m*5+0], g1 = sgt[m*5+1], g2 = sgt[m*5+2], g3 = sgt[m*5+3];
    float l = cx - g0, t = cy - g1, r = g2 - cx, d = g3 - cy;
    float mn = fminf(fminf(l, t), fminf(r, d));
    float mx = fmaxf(fmaxf(l, t), fmaxf(r, d));
    bool  ok = (mn > 0.f) && (mx > lower) && (mx < upper);
    float area = (g2 - g0) * (g3 - g1);
    float q = ok ? (100000000.0f - area) : 0.f;
    if (q > best) { best = q; bi = m; }
  }
  float d0, d1, d2, d3, ctrv;
  if (best < 1e-5f) {
    d0 = d1 = d2 = d3 = -1.f; ctrv = -1.f;
  } else {
    float m0 = sgt[bi*5+0], m1 = sgt[bi*5+1], m2 = sgt[bi*5+2], m3 = sgt[bi*5+3];
    d0 = (cx - m0) / stride; d1 = (cy - m1) / stride;
    d2 = (m2 - cx) / stride; d3 = (m3 - cy) / stride;
    float mnlr = fminf(d0, d2), mntb = fminf(d1, d3);
    float mxlr = fmaxf(d0, d2), mxtb = fmaxf(d1, d3);
    ctrv = sqrtf((mnlr * mntb) / (mxlr * mxtb));
  }
  long dbase = DELTA_OFF + ((long)b * NT + n) * 4;
  if (!bf) {
    *(float4*)((float*)out + dbase) = make_float4(d0, d1, d2, d3);
  } else {
    ushort4 v; v.x = f2bf(d0); v.y = f2bf(d1); v.z = f2bf(d2); v.w = f2bf(d3);
    *(ushort4*)((unsigned short*)out + dbase) = v;
  }
  stout(out, CTR_OFF + (long)b * NT + n, ctrv, bf);

  // ---- scores: argmax over sigmoid == argmax over logits (monotone) ----
  float ct  = ldin(CT, (long)b * NL + nl, bf);
  float sct = 1.0f / (1.0f + expf(-ct));

  float cl[NC];
  long cb = ((long)b * NL + nl) * NC;
  if (!bf) {
    const float4* p = (const float4*)((const float*)CL + cb);   // cb*4 % 16 == 0
#pragma unroll
    for (int i = 0; i < 5; ++i) {
      float4 q = p[i];
      cl[4*i+0] = q.x; cl[4*i+1] = q.y; cl[4*i+2] = q.z; cl[4*i+3] = q.w;
    }
  } else {
    const uint2* p = (const uint2*)((const unsigned short*)CL + cb);  // cb*2 % 8 == 0
#pragma unroll
    for (int i = 0; i < 5; ++i) {
      uint2 q = p[i];
      cl[4*i+0] = __uint_as_float((q.x & 0xFFFFu) << 16);
      cl[4*i+1] = __uint_as_float(q.x & 0xFFFF0000u);
      cl[4*i+2] = __uint_as_float((q.y & 0xFFFFu) << 16);
      cl[4*i+3] = __uint_as_float(q.y & 0xFFFF0000u);
    }
  }
  float vmax = cl[0], v2 = -INFINITY; int ci = 0;
#pragma unroll
  for (int c = 1; c < NC; ++c) {
    if (cl[c] > vmax) { v2 = vmax; vmax = cl[c]; ci = c; }
    else if (cl[c] > v2) v2 = cl[c];
  }
  float smax;
  if (vmax - v2 < 1e-3f) {
    // sigmoid-plateau risk: replicate the reference loop exactly (strict >, first idx)
    smax = -1.0f; ci = 0;
    for (int c = 0; c < NC; ++c) {
      float sv = 1.0f / (1.0f + expf(-cl[c]));
      float s  = sqrtf(sv * sct);
      if (s > smax) { smax = s; ci = c; }
    }
  } else {
    float sv = 1.0f / (1.0f + expf(-vmax));
    smax = sqrtf(sv * sct);      // == ref's max: RN is monotone under *sct and sqrt
  }

  // ---- decode ----
  float r0, r1, r2, r3;
  long rbase = ((long)b * NL + nl) * 4;
  if (!bf) {
    float4 rv = *(const float4*)((const float*)RG + rbase);
    r0 = rv.x; r1 = rv.y; r2 = rv.z; r3 = rv.w;
  } else {
    uint2 rw = *(const uint2*)((const unsigned short*)RG + rbase);
    r0 = __uint_as_float((rw.x & 0xFFFFu) << 16); r1 = __uint_as_float(rw.x & 0xFFFF0000u);
    r2 = __uint_as_float((rw.y & 0xFFFFu) << 16); r3 = __uint_as_float(rw.y & 0xFFFF0000u);
  }
  r0 = fmaxf(r0, 0.f); r1 = fmaxf(r1, 0.f); r2 = fmaxf(r2, 0.f); r3 = fmaxf(r3, 0.f);
  long o = (long)b * NT + n;
  scores[o] = smax;
  *(float4*)(boxesw + o * 4) =
      make_float4(cx - r0 * stride, cy - r1 * stride, cx + r2 * stride, cy + r3 * stride);
  cidw[o] = (float)ci;
}

// ---------- wave64 inclusive scan ----------
__device__ __forceinline__ unsigned wscan(unsigned v, int lane) {
  for (int off = 1; off < 64; off <<= 1) {
    unsigned u = __shfl_up(v, off);
    if (lane >= off) v += u;
  }
  return v;
}

// ---------- K2: top-1000 select + sort + in-block ballot NMS + det write ----------
__global__ __launch_bounds__(1024)
void k_post(const float* scores, const float* boxesw, const float* cidw,
            void* out, const void* locs0) {
  const int bf   = detect_bf(locs0);
  const int b    = blockIdx.x;
  const int tid  = threadIdx.x;
  const int wid  = tid >> 6;
  const int lane = tid & 63;
  const float* sb = scores + (long)b * NT;

  __shared__ unsigned hist[8192];                       // 32 KB; aliased below
  unsigned long long* selKeys = (unsigned long long*)hist;  // [1024], alias
  __shared__ unsigned wsum[16];
  __shared__ unsigned sTop, sBefore, sSub, selCnt;
  __shared__ float redf[16];
  __shared__ float sMaxC;
  __shared__ float sBox[5];                             // picked shifted box + area
  __shared__ unsigned long long smask[16];

  // ============ Phase A: exact top-1000 (2-level histogram + hybrid bitonic) ====
  unsigned inv[21];
#pragma unroll
  for (int k = 0; k < 21; ++k)
    inv[k] = ~__float_as_uint(sb[tid + k * 1024]);

  // level 1: histogram of inv>>17 (top 2 bits always 11 -> 8192 bins)
  for (int i = tid; i < 8192; i += 1024) hist[i] = 0u;
  __syncthreads();
#pragma unroll
  for (int k = 0; k < 21; ++k)
    atomicAdd(&hist[(inv[k] >> 17) - 0x6000u], 1u);
  __syncthreads();
  {
    unsigned hloc[8], s0 = 0;
#pragma unroll
    for (int j = 0; j < 8; ++j) { hloc[j] = hist[8 * tid + j]; s0 += hloc[j]; }
    unsigned sc = wscan(s0, lane);
    if (lane == 63) wsum[wid] = sc;
    __syncthreads();
    unsigned basev = 0;
    for (int w = 0; w < wid; ++w) basev += wsum[w];
    unsigned cumBefore = basev + sc - s0;
    if (cumBefore < TOPK && cumBefore + s0 >= TOPK) {
      unsigned c = cumBefore;
#pragma unroll
      for (int j = 0; j < 8; ++j) {
        if (c + hloc[j] >= TOPK) { sTop = (8 * tid + j) + 0x6000u; sBefore = c; break; }
        c += hloc[j];
      }
    }
  }
  __syncthreads();
  const unsigned topBits = sTop;
  const unsigned r = TOPK - sBefore;

  // level 2: histogram of bits 16..4 within boundary bin
  for (int i = tid; i < 8192; i += 1024) hist[i] = 0u;
  __syncthreads();
#pragma unroll
  for (int k = 0; k < 21; ++k)
    if ((inv[k] >> 17) == topBits) atomicAdd(&hist[(inv[k] >> 4) & 0x1FFFu], 1u);
  __syncthreads();
  {
    unsigned hloc[8], s0 = 0;
#pragma unroll
    for (int j = 0; j < 8; ++j) { hloc[j] = hist[8 * tid + j]; s0 += hloc[j]; }
    unsigned sc = wscan(s0, lane);
    if (lane == 63) wsum[wid] = sc;
    __syncthreads();
    unsigned basev = 0;
    for (int w = 0; w < wid; ++w) basev += wsum[w];
    unsigned cumBefore = basev + sc - s0;
    if (cumBefore < r && cumBefore + s0 >= r) {
      unsigned c = cumBefore;
#pragma unroll
      for (int j = 0; j < 8; ++j) {
        if (c + hloc[j] >= r) { sSub = 8 * tid + j; break; }
        c += hloc[j];
      }
    }
  }
  __syncthreads();
  const unsigned long long cutEnd =
      ((unsigned long long)topBits << 17) | ((unsigned long long)(sSub + 1u) << 4);
  if (tid == 0) selCnt = 0u;
  __syncthreads();   // hist reads done; selKeys alias safe

#pragma unroll
  for (int k = 0; k < 21; ++k)
    if ((unsigned long long)inv[k] < cutEnd) {
      unsigned p = atomicAdd(&selCnt, 1u);
      if (p < 1024u) selKeys[p] = ((unsigned long long)inv[k] << 32) | (unsigned)(tid + k * 1024);
    }
  __syncthreads();
  unsigned total = selCnt < 1024u ? selCnt : 1024u;
  unsigned long long key =
      ((unsigned)tid < total) ? selKeys[tid] : 0xFFFFFFFFFFFFFFFFull;
  __syncthreads();

  // hybrid bitonic sort ascending: (inv asc, idx asc) == (score desc, idx asc)
  for (unsigned k = 2; k <= 1024; k <<= 1) {
    for (unsigned j = k >> 1; j > 0; j >>= 1) {
      unsigned long long other;
      if (j >= 64) {
        selKeys[tid] = key; __syncthreads();
        other = selKeys[tid ^ j]; __syncthreads();
      } else {
        other = __shfl(key, (int)(lane ^ j));
      }
      bool up = ((tid & k) == 0);
      bool takeMin = (((tid & j) == 0) == up);
      key = takeMin ? (key < other ? key : other) : (key > other ? key : other);
    }
  }

  // ---- gather box/score/cls (registers) ----
  float sc = __uint_as_float(~(unsigned)(key >> 32));
  float4 bv = make_float4(0.f, 0.f, 0.f, 0.f);
  float cid = 0.f;
  if (tid < TOPK) {
    long o = (long)b * NT + (unsigned)key;
    bv = *(const float4*)(boxesw + o * 4);
    cid = cidw[o];
  } else sc = 0.f;

  // ---- max_coord = max(where(valid, bx, 0)) ----
  float loc = (tid < TOPK)
      ? ((sc > 0.3f) ? fmaxf(fmaxf(bv.x, bv.y), fmaxf(bv.z, bv.w)) : 0.0f)
      : -INFINITY;
  for (int o = 32; o > 0; o >>= 1) loc = fmaxf(loc, __shfl_down(loc, o));
  if (lane == 0) redf[wid] = loc;
  __syncthreads();
  if (tid == 0) {
    float m = redf[0];
    for (int w = 1; w < 16; ++w) m = fmaxf(m, redf[w]);
    sMaxC = m;
  }
  __syncthreads();

  // ---- shifted box + area, all in registers ----
  float offm = sMaxC + 1.0f;
  float o4 = cid * offm;
  float s0 = bv.x + o4, s1 = bv.y + o4, s2 = bv.z + o4, s3 = bv.w + o4;
  float myArea = (s2 - s0) * (s3 - s1);

  // ---- act init: every wave keeps all 16 act words (word w in lane w) ----
  bool valid = (tid < TOPK) && (sc > 0.3f);
  unsigned long long vb = __ballot(valid);
  if (lane == 0) smask[wid] = vb;
  __syncthreads();
  unsigned long long actW = (lane < 16) ? smask[lane] : 0ull;

  // first pick (computed redundantly by every wave, identically)
  int pick;
  {
    int cand = actW ? (lane * 64 + __ffsll(actW) - 1) : 0x7FFFFFFF;
    for (int o = 8; o > 0; o >>= 1) cand = min(cand, __shfl_down(cand, o));
    pick = __shfl(cand, 0);
    if (pick == 0x7FFFFFFF) pick = -1;
  }

  // ---- greedy NMS: <=100 picks, 2 barriers per pick ----
  bool mykeep = false;
  int kept = 0;
  while (pick >= 0 && kept < 100) {
    if (tid == pick) {
      sBox[0] = s0; sBox[1] = s1; sBox[2] = s2; sBox[3] = s3; sBox[4] = myArea;
      mykeep = true;
    }
    __syncthreads();                     // sBox ready
    float xx1 = fmaxf(sBox[0], s0);
    float yy1 = fmaxf(sBox[1], s1);
    float xx2 = fminf(sBox[2], s2);
    float yy2 = fminf(sBox[3], s3);
    float inter = fmaxf(xx2 - xx1, 0.f) * fmaxf(yy2 - yy1, 0.f);
    float iou = inter / (sBox[4] + myArea - inter);   // exact div: ref rounding
    bool sup = (tid < TOPK) && !(iou <= 0.5f);        // NaN suppresses (self too)
    unsigned long long sm = __ballot(sup);
    if (lane == 0) smask[wid] = sm;
    __syncthreads();                     // all suppression masks ready
    unsigned long long clr = (lane < 16) ? smask[lane] : 0ull;
    actW &= ~clr;
    ++kept;
    int cand = actW ? (lane * 64 + __ffsll(actW) - 1) : 0x7FFFFFFF;
    for (int o = 8; o > 0; o >>= 1) cand = min(cand, __shfl_down(cand, o));
    pick = __shfl(cand, 0);
    if (pick == 0x7FFFFFFF) pick = -1;
  }
  __syncthreads();

  // ---- det write from registers ----
  if (tid < TOPK) {
    long o = ((long)b * TOPK + tid) * 5;
    stout(out, o + 0, mykeep ? bv.x : 0.f, bf);
    stout(out, o + 1, mykeep ? bv.y : 0.f, bf);
    stout(out, o + 2, mykeep ? bv.z : 0.f, bf);
    stout(out, o + 3, mykeep ? bv.w : 0.f, bf);
    stout(out, o + 4, mykeep ? sc   : 0.f, bf);
  }
}

extern "C" void kernel_launch(void* const* d_in, const int* in_sizes, int n_in,
                              void* d_out, int out_size, void* d_ws, size_t ws_size,
                              hipStream_t stream) {
  const void* locs0 = d_in[0];
  const void* locs1 = d_in[1];
  const void* locs2 = d_in[2];
  const void* gt    = d_in[3];

  int ic[3], ir[3], it[3];
  if (n_in >= 13 && in_sizes[5] == 16 * 4096 * 20) {
    ic[0]=4; ic[1]=5; ic[2]=6;  ir[0]=7; ir[1]=8; ir[2]=9;  it[0]=10; it[1]=11; it[2]=12;
  } else {
    ic[0]=4; ic[1]=7; ic[2]=10; ir[0]=5; ir[1]=8; ir[2]=11; it[0]=6;  it[1]=9;  it[2]=12;
  }
  const void* cls0 = d_in[ic[0]]; const void* cls1 = d_in[ic[1]]; const void* cls2 = d_in[ic[2]];
  const void* reg0 = d_in[ir[0]]; const void* reg1 = d_in[ir[1]]; const void* reg2 = d_in[ir[2]];
  const void* ctr0 = d_in[it[0]]; const void* ctr1 = d_in[it[1]]; const void* ctr2 = d_in[it[2]];

  float* ws     = (float*)d_ws;
  float* scores = ws + WS_SCORES;
  float* boxesw = ws + WS_BOXESW;
  float* cidw   = ws + WS_CIDW;

  k_main<<<dim3(NT / 256, NB), 256, 0, stream>>>(locs0, locs1, locs2, gt,
                                                 cls0, cls1, cls2,
                                                 reg0, reg1, reg2,
                                                 ctr0, ctr1, ctr2,
                                                 d_out, scores, boxesw, cidw);
  k_post<<<NB, 1024, 0, stream>>>(scores, boxesw, cidw, d_out, locs0);
}